// Round 3
// baseline (205.995 us; speedup 1.0000x reference)
//
#include <hip/hip_runtime.h>

#define IN_DIM   16384
#define OUT_DIM  16384
#define BATCH    64
#define K_IN     1024
#define K_OUT    1024
#define NPAIRS   (BATCH * K_OUT)   // 65536
#define CAP      64                // bucket capacity per row (P(overflow) ~ 0)
#define HALF     8192              // floats per half-row

// ---------------- prep: fixed-capacity bucket append ------------------------

__global__ void zero_kernel(int* __restrict__ p, int n) {
    int i = blockIdx.x * blockDim.x + threadIdx.x;
    if (i < n) p[i] = 0;
}

__global__ void scatter_kernel(const int* __restrict__ out_idx,
                               int* __restrict__ cursor,
                               int* __restrict__ pairs) {
    int t = blockIdx.x * blockDim.x + threadIdx.x;
    int r = out_idx[t];
    int pos = atomicAdd(&cursor[r], 1);
    if (pos < CAP) pairs[r * CAP + pos] = t;
}

// ---------------- main kernel: one block per (row, half) --------------------
// 32 KB LDS -> 5 blocks/CU (20 waves), so global_load_lds drain stalls of
// one block overlap with staging/compute of the other four.

__launch_bounds__(256)
__global__ void slide_main(const float* __restrict__ in_vals,
                           const float* __restrict__ W,
                           const int*   __restrict__ in_idx,
                           const int*   __restrict__ cnts,
                           const int*   __restrict__ pairs,
                           float*       __restrict__ part) {
    __shared__ float row[HALF];     // 32 KB
    int blk = blockIdx.x;
    int r   = blk >> 1;             // W row
    int h   = blk & 1;              // which half of the row
    int cnt = cnts[r];
    if (cnt == 0) return;           // unreferenced row: skip the stream

    int w    = threadIdx.x >> 6;    // wave 0..3
    int lane = threadIdx.x & 63;

    // async stage: 32 chunks x 1 KB = 32 KB, linear LDS layout
    const float* g = W + (size_t)r * IN_DIM + h * HALF;
    #pragma unroll
    for (int k = 0; k < 8; ++k) {
        int c = k * 4 + w;                                 // chunk 0..31
        __builtin_amdgcn_global_load_lds(
            (const __attribute__((address_space(1))) void*)(g + c * 256 + lane * 4),
            (__attribute__((address_space(3))) void*)(row + c * 256),
            16, 0, 0);
    }
    __syncthreads();

    int base = h * HALF;
    const int* prow = pairs + r * CAP;

    for (int p = w; p < cnt; p += 4) {
        int t  = prow[p];
        int bb = t >> 10;                                   // batch
        const int4*   idx4 = (const int4*)  (in_idx  + bb * K_IN);
        const float4* val4 = (const float4*)(in_vals + bb * K_IN);

        float acc = 0.f;
        #pragma unroll
        for (int i = 0; i < K_IN / 256; ++i) {              // 4 iters
            int4   id = idx4[lane + i * 64];                // coalesced, L2-hot
            float4 v  = val4[lane + i * 64];
            int a0 = id.x - base, a1 = id.y - base,
                a2 = id.z - base, a3 = id.w - base;
            // unconditional in-bounds ds_read; mask via the value operand
            float f0 = row[a0 & (HALF - 1)];
            float f1 = row[a1 & (HALF - 1)];
            float f2 = row[a2 & (HALF - 1)];
            float f3 = row[a3 & (HALF - 1)];
            acc = fmaf(f0, ((unsigned)a0 < HALF) ? v.x : 0.f, acc);
            acc = fmaf(f1, ((unsigned)a1 < HALF) ? v.y : 0.f, acc);
            acc = fmaf(f2, ((unsigned)a2 < HALF) ? v.z : 0.f, acc);
            acc = fmaf(f3, ((unsigned)a3 < HALF) ? v.w : 0.f, acc);
        }
        #pragma unroll
        for (int m = 32; m >= 1; m >>= 1) acc += __shfl_xor(acc, m, 64);
        if (lane == 0) part[h * NPAIRS + t] = acc;
    }
}

// ---------------- combine: out = partLo + partHi + bias ---------------------

__global__ void combine_kernel(const float* __restrict__ part,
                               const float* __restrict__ bias,
                               const int*   __restrict__ out_idx,
                               float*       __restrict__ out) {
    int t = blockIdx.x * blockDim.x + threadIdx.x;
    out[t] = part[t] + part[NPAIRS + t] + bias[out_idx[t]];
}

// ---------------------------------------------------------------------------

extern "C" void kernel_launch(void* const* d_in, const int* in_sizes, int n_in,
                              void* d_out, int out_size, void* d_ws, size_t ws_size,
                              hipStream_t stream) {
    const float* in_vals = (const float*)d_in[0];   // (64,1024) f32
    const float* W       = (const float*)d_in[1];   // (16384,16384) f32
    const float* bias    = (const float*)d_in[2];   // (16384,) f32
    const int*   in_idx  = (const int*)  d_in[3];   // (64,1024) i32
    const int*   out_idx = (const int*)  d_in[4];   // (64,1024) i32
    float*       out     = (float*)d_out;           // (64,1024) f32

    // workspace (ints/floats): cursor[OUT_DIM] | pairs[OUT_DIM*CAP] | part[2*NPAIRS]
    int*   cursor = (int*)d_ws;
    int*   pairs  = cursor + OUT_DIM;
    float* part   = (float*)(pairs + OUT_DIM * CAP);

    zero_kernel   <<<OUT_DIM / 256, 256, 0, stream>>>(cursor, OUT_DIM);
    scatter_kernel<<<NPAIRS / 256, 256, 0, stream>>>(out_idx, cursor, pairs);
    slide_main    <<<2 * OUT_DIM, 256, 0, stream>>>(in_vals, W, in_idx,
                                                    cursor, pairs, part);
    combine_kernel<<<NPAIRS / 256, 256, 0, stream>>>(part, bias, out_idx, out);
}